// Round 10
// baseline (755.679 us; speedup 1.0000x reference)
//
#include <hip/hip_runtime.h>

#define NN 30000
#define NE 120000
#define NG 256
#define FIN 16
#define HD 32
#define TOUT 10
#define EPSV 1e-5f
#define NB_SCAN 30   // ceil(NN/1024)

__device__ __forceinline__ void atomAddF(float* p, float v) {
    unsafeAtomicAdd(p, v);  // global_atomic_add_f32
}

// ---------------------------------------------------------------------------
// Per-edge in-degree count + per-graph node count (run-length on sorted batch)
// ---------------------------------------------------------------------------
__global__ __launch_bounds__(256) void count_deg_kernel(
    const int* __restrict__ eidx, const int* __restrict__ batch,
    int* __restrict__ deg_in, float* __restrict__ deg_g)
{
    const int t = blockIdx.x * 256 + threadIdx.x;
    if (t < NE) atomicAdd(&deg_in[eidx[NE + t]], 1);

    const int lane = threadIdx.x & 63;
    const int g = (t < NN) ? batch[t] : -1;
    const int prev = __shfl_up(g, 1);
    const bool head = (lane == 0) || (g != prev);
    const unsigned long long heads = __ballot(head);
    if (head && g >= 0) {
        const unsigned long long higher =
            (lane < 63) ? (heads >> (lane + 1)) : 0ULL;
        const int next = higher ? (lane + __ffsll(higher)) : 64;
        atomAddF(&deg_g[g], (float)(next - lane));
    }
}

// ---------------------------------------------------------------------------
// Scan phase 1: per-block exclusive scan of deg_in; emit block sums.
// ---------------------------------------------------------------------------
__global__ __launch_bounds__(1024) void scan_phase1(
    const int* __restrict__ deg_in, int* __restrict__ row_start,
    int* __restrict__ blocksum)
{
    __shared__ int wsum[16];
    const int t = threadIdx.x, lane = t & 63, w = t >> 6;
    const int idx = blockIdx.x * 1024 + t;
    const int v = (idx < NN) ? deg_in[idx] : 0;
    int s = v;
    #pragma unroll
    for (int off = 1; off < 64; off <<= 1) {
        const int u = __shfl_up(s, off, 64);
        if (lane >= off) s += u;
    }
    if (lane == 63) wsum[w] = s;
    __syncthreads();
    if (w == 0) {
        int ws = (lane < 16) ? wsum[lane] : 0;
        #pragma unroll
        for (int off = 1; off < 16; off <<= 1) {
            const int u = __shfl_up(ws, off, 64);
            if (lane >= off) ws += u;
        }
        if (lane < 16) wsum[lane] = ws;
    }
    __syncthreads();
    const int incl = s + ((w > 0) ? wsum[w - 1] : 0);
    if (idx < NN) row_start[idx] = incl - v;  // block-local exclusive
    if (t == 1023) blocksum[blockIdx.x] = incl;
}

// ---------------------------------------------------------------------------
// Scan apply: each block reduces blocksum[0..blk) itself and adds offset.
// ---------------------------------------------------------------------------
__global__ __launch_bounds__(1024) void scan_apply(
    const int* __restrict__ blocksum, int* __restrict__ row_start,
    int* __restrict__ cursor)
{
    __shared__ int boff_s;
    const int t = threadIdx.x;
    if (t < 64) {
        int v = (t < blockIdx.x) ? blocksum[t] : 0;   // blockIdx.x <= 29
        #pragma unroll
        for (int off = 32; off > 0; off >>= 1) v += __shfl_down(v, off, 64);
        if (t == 0) boff_s = v;
    }
    __syncthreads();
    const int idx = blockIdx.x * 1024 + t;
    if (idx < NN) {
        const int r = row_start[idx] + boff_s;
        row_start[idx] = r;
        cursor[idx]    = r;
    }
    if (blockIdx.x == 0 && t == 0) row_start[NN] = NE;
}

// ---------------------------------------------------------------------------
// Scatter edges into CSR order; emit (src,dst) pairs and reordered ea.
// ---------------------------------------------------------------------------
__global__ __launch_bounds__(256) void csr_scatter(
    const int* __restrict__ eidx, const float* __restrict__ ea,
    int* __restrict__ cursor,
    int2* __restrict__ sd_s,      // [NE+32] (src, dst)
    float4* __restrict__ ea_s)    // [(NE+32)*2]
{
    const int e = blockIdx.x * 256 + threadIdx.x;
    if (e < NE) {
        const int s = eidx[e];
        const int d = eidx[NE + e];
        const int slot = atomicAdd(&cursor[d], 1);
        sd_s[slot] = make_int2(s, d);
        const float4* s4 = (const float4*)(ea + (size_t)e * 8);
        ea_s[2 * slot]     = s4[0];
        ea_s[2 * slot + 1] = s4[1];
    }
    if (e < 32) {
        sd_s[NE + e] = make_int2(0, 0);   // overshoot pad
        ea_s[2 * (NE + e)]     = make_float4(0.f, 0.f, 0.f, 0.f);
        ea_s[2 * (NE + e) + 1] = make_float4(0.f, 0.f, 0.f, 0.f);
    }
}

// ===========================================================================
// Fused layer. Block = 16 nodes, 4 waves.
// Phase A (FLAT, edge-parallel): block's CSR slots are contiguous
// [row_s[16b], row_s[16b+16]). 256/IN edge-groups sweep the range uniformly;
// each edge: load (src,dst)+ea (broadcast) + hin[src] row (coalesced),
// then 9 ds_add_f32 into T[dst-local]. No per-node serial chains, no
// degree-tail imbalance inside the block, no shfl transposes.
// Phase B: k split across 4 waves x 2 halves; W slice in registers (loaded
// after phase A); T read as half-wave-broadcast b128; merge into Acc via
// ds_add; epilogue gsn+BN+ReLU or pooled atomics.
// ===========================================================================
template<int IN, bool FINAL>
__global__ __launch_bounds__(256, 8) void fused_layer(
    const float* __restrict__ hin,       // [NN, IN]
    const int2*  __restrict__ sd_s,      // [NE+32] CSR-ordered (src,dst)
    const float4* __restrict__ ea_s,     // [(NE+32)*2] CSR-ordered edge attrs
    const int*   __restrict__ row_start, // [NN+1]
    const float* __restrict__ nn_w,      // [8*IN*32] flat k*32+o
    const float* __restrict__ nn_b,      // [IN*32]
    const float* __restrict__ root,      // [IN*32]
    const float* __restrict__ bias,      // [32]
    const int*   __restrict__ batch,
    const float* __restrict__ deg_g,     // [NG]
    const float* __restrict__ bn_g,
    const float* __restrict__ bn_b,
    const float* __restrict__ bn_m,
    const float* __restrict__ bn_v,
    float*       __restrict__ out)       // [NN,32] or pooled [NG,32]
{
    constexpr int K   = 10 * IN;
    constexpr int KP  = K + 4;    // row pad: staggers ds_add banks (IN=16)
    constexpr int KQ  = K / 4;    // per-wave k-slice
    constexpr int KL  = K / 8;    // per-half-lane W registers
    constexpr int EPG = 256 / IN; // edges processed per block pass

    __shared__ float Tlds[16 * KP];
    __shared__ float Acc[16 * 32];

    const int tid  = threadIdx.x;
    const int wv   = tid >> 6;
    const int l    = tid & 63;
    const int h    = l >> 5;
    const int o    = l & 31;
    const int base = blockIdx.x * 16;

    // ---- init: zero T rows 0..8, stage own rows (row 9), bias into Acc ----
    {
        // BUGFIX (R9): grid-stride with explicit bound — the old compile-time
        // trip count floor-divided and left the last ~1.5 nodes' T rows
        // uninitialized (NaN).
        float4* tz = (float4*)Tlds;
        constexpr int NZ4 = (16 * 9 * IN) / 4;     // float4s to zero
        constexpr int C4  = (9 * IN) / 4;          // float4s per node row
        for (int idx = tid; idx < NZ4; idx += 256) {
            const int n = idx / C4;
            const int c = idx % C4;
            tz[n * (KP / 4) + c] = make_float4(0.f, 0.f, 0.f, 0.f);
        }
        #pragma unroll
        for (int r = 0; r < (16 * IN) / 256; ++r) {
            const int idx = r * 256 + tid;         // flat 0..16*IN
            Tlds[(idx / IN) * KP + 9 * IN + (idx % IN)] =
                hin[(long)base * IN + idx];
        }
        Acc[tid]       = bias[o];
        Acc[256 + tid] = bias[o];
    }
    __syncthreads();

    // ---------------- phase A: flat edge sweep, ds_add accumulate ---------
    {
        const int i = tid % IN;
        const int s = tid / IN;           // edge-group id, 0..EPG-1
        const int e0 = row_start[base];
        const int e1 = row_start[base + 16];

        int p = e0 + s;
        if (p < e1) {
            int2   sd_c = sd_s[p];
            float4 a_c  = ea_s[2 * p];
            float4 b_c  = ea_s[2 * p + 1];
            float  xv   = hin[(long)sd_c.x * IN + i];

            while (true) {
                const int pn = p + EPG;
                const int2   sd_n = sd_s[pn];          // pad-safe
                const float4 a_n  = ea_s[2 * pn];
                const float4 b_n  = ea_s[2 * pn + 1];
                const float  xvn  = hin[(long)sd_n.x * IN + i];

                float* tr = Tlds + (sd_c.y - base) * KP + i;
                atomicAdd(tr + 0 * IN, a_c.x * xv);    // ds_add_f32
                atomicAdd(tr + 1 * IN, a_c.y * xv);
                atomicAdd(tr + 2 * IN, a_c.z * xv);
                atomicAdd(tr + 3 * IN, a_c.w * xv);
                atomicAdd(tr + 4 * IN, b_c.x * xv);
                atomicAdd(tr + 5 * IN, b_c.y * xv);
                atomicAdd(tr + 6 * IN, b_c.z * xv);
                atomicAdd(tr + 7 * IN, b_c.w * xv);
                atomicAdd(tr + 8 * IN, xv);

                p = pn;
                if (p >= e1) break;
                sd_c = sd_n; a_c = a_n; b_c = b_n; xv = xvn;
            }
        }
    }
    __syncthreads();

    // ---- W slice into registers AFTER barrier (no overlap w/ phase A) ----
    float Wreg[KL];
    const int kbase = wv * KQ + h * KL;
    #pragma unroll
    for (int kk = 0; kk < KL; ++kk) {
        const int k = kbase + kk;
        const float* src = (k < 8 * IN) ? (nn_w + k * 32)
                         : (k < 9 * IN) ? (nn_b + (k - 8 * IN) * 32)
                                        : (root + (k - 9 * IN) * 32);
        Wreg[kk] = src[o];
    }

    // ---------------- phase B: partial GEMM, merge into Acc ---------------
    for (int n = 0; n < 16; ++n) {
        const float* tb = Tlds + n * KP + kbase;
        float acc = 0.0f;
        #pragma unroll
        for (int kq = 0; kq < KL / 4; ++kq) {
            const float4 tv = *(const float4*)(tb + kq * 4);
            acc = fmaf(Wreg[4 * kq + 0], tv.x, acc);
            acc = fmaf(Wreg[4 * kq + 1], tv.y, acc);
            acc = fmaf(Wreg[4 * kq + 2], tv.z, acc);
            acc = fmaf(Wreg[4 * kq + 3], tv.w, acc);
        }
        acc += __shfl_xor(acc, 32, 64);
        if (h == 0) atomicAdd(&Acc[n * 32 + o], acc);   // ds_add_f32
    }
    __syncthreads();

    // ---------------- epilogue ---------------------------------------------
    #pragma unroll
    for (int r = 0; r < 2; ++r) {
        const int idx = r * 256 + tid;          // 512 (n,o) pairs
        const int n   = idx >> 5;
        const int oo  = idx & 31;
        float sum = Acc[idx];
        const int d = base + n;
        const int g = batch[d];
        if (!FINAL) {
            float dg = deg_g[g];
            dg = dg > 0.0f ? dg : 1.0f;
            float v = sum * (1.0f / sqrtf(dg));
            const float s = bn_g[oo] / sqrtf(bn_v[oo] + EPSV);
            v = (v - bn_m[oo]) * s + bn_b[oo];
            out[(long)d * 32 + oo] = v > 0.0f ? v : 0.0f;
        } else {
            float v = sum;
            const int   g2 = __shfl(g, (tid & 63) ^ 32, 64);
            const float v2 = __shfl(v, (tid & 63) ^ 32, 64);
            bool do_store = true;
            if (g2 == g) {                  // merge adjacent-node pair
                if (tid & 32) do_store = false;
                else          v += v2;
            }
            if (do_store) atomAddF(&out[g * 32 + oo], v);
        }
    }
}

// ---------------------------------------------------------------------------
// Head: pooled/cnt -> relu(@w1+b1) @ w2 + b2. One thread per graph.
// ---------------------------------------------------------------------------
__global__ __launch_bounds__(64) void head_kernel(
    const float* __restrict__ pooled,
    const float* __restrict__ deg,
    const float* __restrict__ w1,
    const float* __restrict__ b1,
    const float* __restrict__ w2,
    const float* __restrict__ b2,
    float*       __restrict__ out)
{
    const int g = blockIdx.x * 64 + threadIdx.x;
    if (g >= NG) return;
    float cnt = deg[g];
    cnt = cnt > 1.0f ? cnt : 1.0f;

    float p[HD];
    #pragma unroll
    for (int i = 0; i < HD; ++i) p[i] = pooled[g * HD + i] / cnt;

    float hid[HD];
    #pragma unroll
    for (int j = 0; j < HD; ++j) {
        float a = b1[j];
        #pragma unroll
        for (int i = 0; i < HD; ++i)
            a = fmaf(p[i], w1[i * HD + j], a);
        hid[j] = a > 0.0f ? a : 0.0f;
    }
    #pragma unroll
    for (int t = 0; t < TOUT; ++t) {
        float a = b2[t];
        #pragma unroll
        for (int j = 0; j < HD; ++j)
            a = fmaf(hid[j], w2[j * TOUT + t], a);
        out[g * TOUT + t] = a;
    }
}

// ---------------------------------------------------------------------------
extern "C" void kernel_launch(void* const* d_in, const int* in_sizes, int n_in,
                              void* d_out, int out_size, void* d_ws, size_t ws_size,
                              hipStream_t stream)
{
    const float* x        = (const float*)d_in[0];
    const float* ea       = (const float*)d_in[1];
    const int*   eidx     = (const int*)  d_in[2];
    const int*   batch    = (const int*)  d_in[3];
    const float* c1_nn_w  = (const float*)d_in[4];
    const float* c1_nn_b  = (const float*)d_in[5];
    const float* c1_root  = (const float*)d_in[6];
    const float* c1_bias  = (const float*)d_in[7];
    const float* c2_nn_w  = (const float*)d_in[8];
    const float* c2_nn_b  = (const float*)d_in[9];
    const float* c2_root  = (const float*)d_in[10];
    const float* c2_bias  = (const float*)d_in[11];
    const float* c3_nn_w  = (const float*)d_in[12];
    const float* c3_nn_b  = (const float*)d_in[13];
    const float* c3_root  = (const float*)d_in[14];
    const float* c3_bias  = (const float*)d_in[15];
    const float* bn1_g    = (const float*)d_in[16];
    const float* bn1_b    = (const float*)d_in[17];
    const float* bn1_m    = (const float*)d_in[18];
    const float* bn1_v    = (const float*)d_in[19];
    const float* bn2_g    = (const float*)d_in[20];
    const float* bn2_b    = (const float*)d_in[21];
    const float* bn2_m    = (const float*)d_in[22];
    const float* bn2_v    = (const float*)d_in[23];
    const float* mlp_w1   = (const float*)d_in[24];
    const float* mlp_b1   = (const float*)d_in[25];
    const float* mlp_w2   = (const float*)d_in[26];
    const float* mlp_b2   = (const float*)d_in[27];
    float* out = (float*)d_out;

    // workspace layout; deg_in, deg_g, pooled are contiguous (one memset)
    int2*   sd_s   = (int2*)d_ws;                   // NE+32
    float4* ea_s   = (float4*)(sd_s + NE + 32);     // 2*(NE+32)
    float*  h1     = (float*)(ea_s + 2 * (NE + 32));// NN*32
    float*  h2     = h1 + NN * HD;                  // NN*32
    int*    deg_in = (int*)(h2 + NN * HD);          // NN
    float*  deg_g  = (float*)(deg_in + NN);         // NG
    float*  pooled = deg_g + NG;                    // NG*32
    int*    row_s  = (int*)(pooled + NG * HD);      // NN+1
    int*    cursor = row_s + NN + 1;                // NN
    int*    bsum   = cursor + NN;                   // NB_SCAN

    hipMemsetAsync(deg_in, 0, sizeof(int) * (NN + NG + NG * HD), stream);

    const int egrid = (NE + 255) / 256;

    count_deg_kernel<<<egrid, 256, 0, stream>>>(eidx, batch, deg_in, deg_g);
    scan_phase1<<<NB_SCAN, 1024, 0, stream>>>(deg_in, row_s, bsum);
    scan_apply <<<NB_SCAN, 1024, 0, stream>>>(bsum, row_s, cursor);
    csr_scatter<<<egrid, 256, 0, stream>>>(eidx, ea, cursor, sd_s, ea_s);

    const int lgrid = NN / 16;  // 1875 blocks, 16 nodes each

    fused_layer<FIN, false><<<lgrid, 256, 0, stream>>>(
        x, sd_s, ea_s, row_s, c1_nn_w, c1_nn_b, c1_root, c1_bias,
        batch, deg_g, bn1_g, bn1_b, bn1_m, bn1_v, h1);

    fused_layer<HD, false><<<lgrid, 256, 0, stream>>>(
        h1, sd_s, ea_s, row_s, c2_nn_w, c2_nn_b, c2_root, c2_bias,
        batch, deg_g, bn2_g, bn2_b, bn2_m, bn2_v, h2);

    fused_layer<HD, true><<<lgrid, 256, 0, stream>>>(
        h2, sd_s, ea_s, row_s, c3_nn_w, c3_nn_b, c3_root, c3_bias,
        batch, deg_g, nullptr, nullptr, nullptr, nullptr, pooled);

    head_kernel<<<(NG + 63) / 64, 64, 0, stream>>>(pooled, deg_g, mlp_w1, mlp_b1,
                                                   mlp_w2, mlp_b2, out);
}

// Round 11
// 280.315 us; speedup vs baseline: 2.6958x; 2.6958x over previous
//
#include <hip/hip_runtime.h>

#define NN 30000
#define NE 120000
#define NG 256
#define FIN 16
#define HD 32
#define TOUT 10
#define EPSV 1e-5f
#define NB_SCAN 30   // ceil(NN/1024)

__device__ __forceinline__ void atomAddF(float* p, float v) {
    unsafeAtomicAdd(p, v);  // global_atomic_add_f32
}

// ---------------------------------------------------------------------------
// Per-edge in-degree count + per-graph node count (run-length on sorted batch)
// ---------------------------------------------------------------------------
__global__ __launch_bounds__(256) void count_deg_kernel(
    const int* __restrict__ eidx, const int* __restrict__ batch,
    int* __restrict__ deg_in, float* __restrict__ deg_g)
{
    const int t = blockIdx.x * 256 + threadIdx.x;
    if (t < NE) atomicAdd(&deg_in[eidx[NE + t]], 1);

    const int lane = threadIdx.x & 63;
    const int g = (t < NN) ? batch[t] : -1;
    const int prev = __shfl_up(g, 1);
    const bool head = (lane == 0) || (g != prev);
    const unsigned long long heads = __ballot(head);
    if (head && g >= 0) {
        const unsigned long long higher =
            (lane < 63) ? (heads >> (lane + 1)) : 0ULL;
        const int next = higher ? (lane + __ffsll(higher)) : 64;
        atomAddF(&deg_g[g], (float)(next - lane));
    }
}

// ---------------------------------------------------------------------------
// Scan phase 1: per-block exclusive scan of deg_in; emit block sums.
// ---------------------------------------------------------------------------
__global__ __launch_bounds__(1024) void scan_phase1(
    const int* __restrict__ deg_in, int* __restrict__ row_start,
    int* __restrict__ blocksum)
{
    __shared__ int wsum[16];
    const int t = threadIdx.x, lane = t & 63, w = t >> 6;
    const int idx = blockIdx.x * 1024 + t;
    const int v = (idx < NN) ? deg_in[idx] : 0;
    int s = v;
    #pragma unroll
    for (int off = 1; off < 64; off <<= 1) {
        const int u = __shfl_up(s, off, 64);
        if (lane >= off) s += u;
    }
    if (lane == 63) wsum[w] = s;
    __syncthreads();
    if (w == 0) {
        int ws = (lane < 16) ? wsum[lane] : 0;
        #pragma unroll
        for (int off = 1; off < 16; off <<= 1) {
            const int u = __shfl_up(ws, off, 64);
            if (lane >= off) ws += u;
        }
        if (lane < 16) wsum[lane] = ws;
    }
    __syncthreads();
    const int incl = s + ((w > 0) ? wsum[w - 1] : 0);
    if (idx < NN) row_start[idx] = incl - v;  // block-local exclusive
    if (t == 1023) blocksum[blockIdx.x] = incl;
}

// ---------------------------------------------------------------------------
// Scan apply: each block reduces blocksum[0..blk) itself and adds offset.
// ---------------------------------------------------------------------------
__global__ __launch_bounds__(1024) void scan_apply(
    const int* __restrict__ blocksum, int* __restrict__ row_start,
    int* __restrict__ cursor)
{
    __shared__ int boff_s;
    const int t = threadIdx.x;
    if (t < 64) {
        int v = (t < blockIdx.x) ? blocksum[t] : 0;   // blockIdx.x <= 29
        #pragma unroll
        for (int off = 32; off > 0; off >>= 1) v += __shfl_down(v, off, 64);
        if (t == 0) boff_s = v;
    }
    __syncthreads();
    const int idx = blockIdx.x * 1024 + t;
    if (idx < NN) {
        const int r = row_start[idx] + boff_s;
        row_start[idx] = r;
        cursor[idx]    = r;
    }
    if (blockIdx.x == 0 && t == 0) row_start[NN] = NE;
}

// ---------------------------------------------------------------------------
// Scatter edges into CSR order; reorder src ids and ea. Pad slot NE zeroed
// (clamp target for the layer's pipeline overshoot).
// ---------------------------------------------------------------------------
__global__ __launch_bounds__(256) void csr_scatter(
    const int* __restrict__ eidx, const float* __restrict__ ea,
    int* __restrict__ cursor,
    int* __restrict__ src_s,      // [NE+8]
    float4* __restrict__ ea_s)    // [(NE+8)*2]
{
    const int e = blockIdx.x * 256 + threadIdx.x;
    if (e < NE) {
        const int d = eidx[NE + e];
        const int slot = atomicAdd(&cursor[d], 1);
        src_s[slot] = eidx[e];
        const float4* s4 = (const float4*)(ea + (size_t)e * 8);
        ea_s[2 * slot]     = s4[0];
        ea_s[2 * slot + 1] = s4[1];
    }
    if (e < 8) {
        src_s[NE + e] = 0;                                // safe hin row
        ea_s[2 * (NE + e)]     = make_float4(0.f, 0.f, 0.f, 0.f);
        ea_s[2 * (NE + e) + 1] = make_float4(0.f, 0.f, 0.f, 0.f);
    }
}

// ===========================================================================
// Fused layer. Block = 16 nodes, 4 waves. __launch_bounds__(256,4): allow
// ~128 VGPRs — registers are spent on memory-level parallelism.
// Phase A: each half-wave runs its TWO nodes' edge chains CONCURRENTLY in
// one fused loop (trip = max of the two, pad-clamped; 9th term masked).
// src ids prefetched depth-2, payload (ea, x-row) depth-1 -> no iteration
// stacks the src->hin dependent latency; ~8 loads in flight per wave.
// Phase B: k split across 4 waves x 2 halves; W slice in registers (loaded
// after phase A); T read as half-wave-broadcast b128; merge into Acc via
// ds_add; epilogue gsn+BN+ReLU or pooled atomics.
// ===========================================================================
template<int IN, bool FINAL>
__global__ __launch_bounds__(256, 4) void fused_layer(
    const float* __restrict__ hin,       // [NN, IN]
    const int*   __restrict__ src_s,     // [NE+8] CSR-ordered src ids
    const float4* __restrict__ ea_s,     // [(NE+8)*2] CSR-ordered edge attrs
    const int*   __restrict__ row_start, // [NN+1]
    const float* __restrict__ nn_w,      // [8*IN*32] flat k*32+o
    const float* __restrict__ nn_b,      // [IN*32]
    const float* __restrict__ root,      // [IN*32]
    const float* __restrict__ bias,      // [32]
    const int*   __restrict__ batch,
    const float* __restrict__ deg_g,     // [NG]
    const float* __restrict__ bn_g,
    const float* __restrict__ bn_b,
    const float* __restrict__ bn_m,
    const float* __restrict__ bn_v,
    float*       __restrict__ out)       // [NN,32] or pooled [NG,32]
{
    constexpr int K   = 10 * IN;
    constexpr int KP  = K + 4;    // keeps rows 16B-aligned (KP%4==0)
    constexpr int KQ  = K / 4;    // per-wave k-slice
    constexpr int KL  = K / 8;    // per-half-lane W registers
    constexpr int NQ  = 32 / IN;  // edge subgroups per node (1 or 2)
    constexpr int PADS = NE;      // zeroed pad slot

    __shared__ float Tlds[16 * KP];
    __shared__ float Acc[16 * 32];

    const int tid  = threadIdx.x;
    const int wv   = tid >> 6;
    const int l    = tid & 63;
    const int h    = l >> 5;
    const int o    = l & 31;
    const int l5   = l & 31;
    const int pr   = l >> 5;
    const int base = blockIdx.x * 16;

    // ---- init: stage own rows (row 9), bias into Acc ----
    {
        #pragma unroll
        for (int r = 0; r < (16 * IN + 255) / 256; ++r) {
            const int idx = r * 256 + tid;
            if (idx < 16 * IN)
                Tlds[(idx / IN) * KP + 9 * IN + (idx % IN)] =
                    hin[(long)base * IN + idx];
        }
        Acc[tid]       = bias[o];
        Acc[256 + tid] = bias[o];
    }

    // ---------------- phase A: dual concurrent edge chains ----------------
    const int i  = l5 & (IN - 1);
    const int q  = l5 / IN;
    const int nA = wv * 4 + pr * 2;
    const int nB = nA + 1;

    const int pA1 = row_start[base + nA + 1];
    const int pB1 = row_start[base + nB + 1];
    int pA = row_start[base + nA] + q;
    int pB = row_start[base + nB] + q;

    float tA[9], tB[9];
    #pragma unroll
    for (int f = 0; f < 9; ++f) { tA[f] = 0.f; tB[f] = 0.f; }

    int pAn = pA + NQ, pBn = pB + NQ;

    // stage 0: current payload + next src prefetch
    const int cA0 = (pA < pA1) ? pA : PADS;
    const int cB0 = (pB < pB1) ? pB : PADS;
    float mA = (pA < pA1) ? 1.f : 0.f;
    float mB = (pB < pB1) ? 1.f : 0.f;
    int cAn = (pAn < pA1) ? pAn : PADS;
    int cBn = (pBn < pB1) ? pBn : PADS;
    float mAn = (pAn < pA1) ? 1.f : 0.f;
    float mBn = (pBn < pB1) ? 1.f : 0.f;
    const int sA0 = src_s[cA0];
    const int sB0 = src_s[cB0];
    int sAn = src_s[cAn];
    int sBn = src_s[cBn];
    float4 aA = ea_s[2 * cA0], bA = ea_s[2 * cA0 + 1];
    float4 aB = ea_s[2 * cB0], bB = ea_s[2 * cB0 + 1];
    float xvA = hin[(long)sA0 * IN + i];
    float xvB = hin[(long)sB0 * IN + i];

    while (pA < pA1 || pB < pB1) {
        const int pAn2 = pAn + NQ, pBn2 = pBn + NQ;
        const int cAn2 = (pAn2 < pA1) ? pAn2 : PADS;
        const int cBn2 = (pBn2 < pB1) ? pBn2 : PADS;
        const float mAn2 = (pAn2 < pA1) ? 1.f : 0.f;
        const float mBn2 = (pBn2 < pB1) ? 1.f : 0.f;
        const int sAn2 = src_s[cAn2];            // src depth-2
        const int sBn2 = src_s[cBn2];
        const float4 aAn = ea_s[2 * cAn];        // payload depth-1
        const float4 bAn = ea_s[2 * cAn + 1];
        const float4 aBn = ea_s[2 * cBn];
        const float4 bBn = ea_s[2 * cBn + 1];
        const float xvAn = hin[(long)sAn * IN + i];
        const float xvBn = hin[(long)sBn * IN + i];

        tA[0] = fmaf(aA.x, xvA, tA[0]);
        tA[1] = fmaf(aA.y, xvA, tA[1]);
        tA[2] = fmaf(aA.z, xvA, tA[2]);
        tA[3] = fmaf(aA.w, xvA, tA[3]);
        tA[4] = fmaf(bA.x, xvA, tA[4]);
        tA[5] = fmaf(bA.y, xvA, tA[5]);
        tA[6] = fmaf(bA.z, xvA, tA[6]);
        tA[7] = fmaf(bA.w, xvA, tA[7]);
        tA[8] = fmaf(mA, xvA, tA[8]);

        tB[0] = fmaf(aB.x, xvB, tB[0]);
        tB[1] = fmaf(aB.y, xvB, tB[1]);
        tB[2] = fmaf(aB.z, xvB, tB[2]);
        tB[3] = fmaf(aB.w, xvB, tB[3]);
        tB[4] = fmaf(bB.x, xvB, tB[4]);
        tB[5] = fmaf(bB.y, xvB, tB[5]);
        tB[6] = fmaf(bB.z, xvB, tB[6]);
        tB[7] = fmaf(bB.w, xvB, tB[7]);
        tB[8] = fmaf(mB, xvB, tB[8]);

        pA = pAn; pB = pBn; pAn = pAn2; pBn = pBn2;
        cAn = cAn2; cBn = cBn2; sAn = sAn2; sBn = sBn2;
        aA = aAn; bA = bAn; xvA = xvAn; mA = mAn; mAn = mAn2;
        aB = aBn; bB = bBn; xvB = xvBn; mB = mBn; mBn = mBn2;
    }

    if (IN == 16) {   // combine the 2 edge subgroups (same i)
        #pragma unroll
        for (int f = 0; f < 9; ++f) {
            tA[f] += __shfl_xor(tA[f], 16, 64);
            tB[f] += __shfl_xor(tB[f], 16, 64);
        }
    }

    if (IN == 32 || (l5 & 16) == 0) {
        float* ta = Tlds + nA * KP;
        float* tb = Tlds + nB * KP;
        #pragma unroll
        for (int f = 0; f < 9; ++f) {
            ta[f * IN + i] = tA[f];
            tb[f * IN + i] = tB[f];
        }
    }
    __syncthreads();

    // ---- W slice into registers AFTER barrier (no overlap w/ phase A) ----
    float Wreg[KL];
    const int kbase = wv * KQ + h * KL;
    #pragma unroll
    for (int kk = 0; kk < KL; ++kk) {
        const int k = kbase + kk;
        const float* src = (k < 8 * IN) ? (nn_w + k * 32)
                         : (k < 9 * IN) ? (nn_b + (k - 8 * IN) * 32)
                                        : (root + (k - 9 * IN) * 32);
        Wreg[kk] = src[o];
    }

    // ---------------- phase B: partial GEMM, merge into Acc ---------------
    for (int n = 0; n < 16; ++n) {
        const float* tb = Tlds + n * KP + kbase;
        float acc = 0.0f;
        #pragma unroll
        for (int kq = 0; kq < KL / 4; ++kq) {
            const float4 tv = *(const float4*)(tb + kq * 4);
            acc = fmaf(Wreg[4 * kq + 0], tv.x, acc);
            acc = fmaf(Wreg[4 * kq + 1], tv.y, acc);
            acc = fmaf(Wreg[4 * kq + 2], tv.z, acc);
            acc = fmaf(Wreg[4 * kq + 3], tv.w, acc);
        }
        acc += __shfl_xor(acc, 32, 64);
        if (h == 0) atomicAdd(&Acc[n * 32 + o], acc);   // ds_add_f32
    }
    __syncthreads();

    // ---------------- epilogue ---------------------------------------------
    #pragma unroll
    for (int r = 0; r < 2; ++r) {
        const int idx = r * 256 + tid;          // 512 (n,o) pairs
        const int n   = idx >> 5;
        const int oo  = idx & 31;
        float sum = Acc[idx];
        const int d = base + n;
        const int g = batch[d];
        if (!FINAL) {
            float dg = deg_g[g];
            dg = dg > 0.0f ? dg : 1.0f;
            float v = sum * (1.0f / sqrtf(dg));
            const float s = bn_g[oo] / sqrtf(bn_v[oo] + EPSV);
            v = (v - bn_m[oo]) * s + bn_b[oo];
            out[(long)d * 32 + oo] = v > 0.0f ? v : 0.0f;
        } else {
            float v = sum;
            const int   g2 = __shfl(g, (tid & 63) ^ 32, 64);
            const float v2 = __shfl(v, (tid & 63) ^ 32, 64);
            bool do_store = true;
            if (g2 == g) {                  // merge adjacent-node pair
                if (tid & 32) do_store = false;
                else          v += v2;
            }
            if (do_store) atomAddF(&out[g * 32 + oo], v);
        }
    }
}

// ---------------------------------------------------------------------------
// Head: pooled/cnt -> relu(@w1+b1) @ w2 + b2. One thread per graph.
// ---------------------------------------------------------------------------
__global__ __launch_bounds__(64) void head_kernel(
    const float* __restrict__ pooled,
    const float* __restrict__ deg,
    const float* __restrict__ w1,
    const float* __restrict__ b1,
    const float* __restrict__ w2,
    const float* __restrict__ b2,
    float*       __restrict__ out)
{
    const int g = blockIdx.x * 64 + threadIdx.x;
    if (g >= NG) return;
    float cnt = deg[g];
    cnt = cnt > 1.0f ? cnt : 1.0f;

    float p[HD];
    #pragma unroll
    for (int i = 0; i < HD; ++i) p[i] = pooled[g * HD + i] / cnt;

    float hid[HD];
    #pragma unroll
    for (int j = 0; j < HD; ++j) {
        float a = b1[j];
        #pragma unroll
        for (int i = 0; i < HD; ++i)
            a = fmaf(p[i], w1[i * HD + j], a);
        hid[j] = a > 0.0f ? a : 0.0f;
    }
    #pragma unroll
    for (int t = 0; t < TOUT; ++t) {
        float a = b2[t];
        #pragma unroll
        for (int j = 0; j < HD; ++j)
            a = fmaf(hid[j], w2[j * TOUT + t], a);
        out[g * TOUT + t] = a;
    }
}

// ---------------------------------------------------------------------------
extern "C" void kernel_launch(void* const* d_in, const int* in_sizes, int n_in,
                              void* d_out, int out_size, void* d_ws, size_t ws_size,
                              hipStream_t stream)
{
    const float* x        = (const float*)d_in[0];
    const float* ea       = (const float*)d_in[1];
    const int*   eidx     = (const int*)  d_in[2];
    const int*   batch    = (const int*)  d_in[3];
    const float* c1_nn_w  = (const float*)d_in[4];
    const float* c1_nn_b  = (const float*)d_in[5];
    const float* c1_root  = (const float*)d_in[6];
    const float* c1_bias  = (const float*)d_in[7];
    const float* c2_nn_w  = (const float*)d_in[8];
    const float* c2_nn_b  = (const float*)d_in[9];
    const float* c2_root  = (const float*)d_in[10];
    const float* c2_bias  = (const float*)d_in[11];
    const float* c3_nn_w  = (const float*)d_in[12];
    const float* c3_nn_b  = (const float*)d_in[13];
    const float* c3_root  = (const float*)d_in[14];
    const float* c3_bias  = (const float*)d_in[15];
    const float* bn1_g    = (const float*)d_in[16];
    const float* bn1_b    = (const float*)d_in[17];
    const float* bn1_m    = (const float*)d_in[18];
    const float* bn1_v    = (const float*)d_in[19];
    const float* bn2_g    = (const float*)d_in[20];
    const float* bn2_b    = (const float*)d_in[21];
    const float* bn2_m    = (const float*)d_in[22];
    const float* bn2_v    = (const float*)d_in[23];
    const float* mlp_w1   = (const float*)d_in[24];
    const float* mlp_b1   = (const float*)d_in[25];
    const float* mlp_w2   = (const float*)d_in[26];
    const float* mlp_b2   = (const float*)d_in[27];
    float* out = (float*)d_out;

    // workspace layout; deg_in, deg_g, pooled are contiguous (one memset)
    float4* ea_s   = (float4*)d_ws;                 // 2*(NE+8)
    int*    src_s  = (int*)(ea_s + 2 * (NE + 8));   // NE+8
    float*  h1     = (float*)(src_s + NE + 8);      // NN*32
    float*  h2     = h1 + NN * HD;                  // NN*32
    int*    deg_in = (int*)(h2 + NN * HD);          // NN
    float*  deg_g  = (float*)(deg_in + NN);         // NG
    float*  pooled = deg_g + NG;                    // NG*32
    int*    row_s  = (int*)(pooled + NG * HD);      // NN+1
    int*    cursor = row_s + NN + 1;                // NN
    int*    bsum   = cursor + NN;                   // NB_SCAN

    hipMemsetAsync(deg_in, 0, sizeof(int) * (NN + NG + NG * HD), stream);

    const int egrid = (NE + 255) / 256;

    count_deg_kernel<<<egrid, 256, 0, stream>>>(eidx, batch, deg_in, deg_g);
    scan_phase1<<<NB_SCAN, 1024, 0, stream>>>(deg_in, row_s, bsum);
    scan_apply <<<NB_SCAN, 1024, 0, stream>>>(bsum, row_s, cursor);
    csr_scatter<<<egrid, 256, 0, stream>>>(eidx, ea, cursor, src_s, ea_s);

    const int lgrid = NN / 16;  // 1875 blocks, 16 nodes each

    fused_layer<FIN, false><<<lgrid, 256, 0, stream>>>(
        x, src_s, ea_s, row_s, c1_nn_w, c1_nn_b, c1_root, c1_bias,
        batch, deg_g, bn1_g, bn1_b, bn1_m, bn1_v, h1);

    fused_layer<HD, false><<<lgrid, 256, 0, stream>>>(
        h1, src_s, ea_s, row_s, c2_nn_w, c2_nn_b, c2_root, c2_bias,
        batch, deg_g, bn2_g, bn2_b, bn2_m, bn2_v, h2);

    fused_layer<HD, true><<<lgrid, 256, 0, stream>>>(
        h2, src_s, ea_s, row_s, c3_nn_w, c3_nn_b, c3_root, c3_bias,
        batch, deg_g, nullptr, nullptr, nullptr, nullptr, pooled);

    head_kernel<<<(NG + 63) / 64, 64, 0, stream>>>(pooled, deg_g, mlp_w1, mlp_b1,
                                                   mlp_w2, mlp_b2, out);
}